// Round 19
// baseline (520.564 us; speedup 1.0000x reference)
//
#include <hip/hip_runtime.h>
#include <stdint.h>

typedef unsigned short ushort_t;
typedef unsigned long long u64_t;
typedef __attribute__((ext_vector_type(4))) float f32x4;
typedef __attribute__((ext_vector_type(8))) short s16x8;

#define S1_ELEMS ((size_t)1568*64*512)   // 51,380,224 elements per q/k/v/x buffer

// ---------- bf16 helpers (RNE)
__device__ __forceinline__ ushort_t f2bf(float f) {
  unsigned u = __builtin_bit_cast(unsigned, f);
  u = u + 0x7fffu + ((u >> 16) & 1u);
  return (ushort_t)(u >> 16);
}
__device__ __forceinline__ float bf2f(ushort_t b) {
  unsigned u = ((unsigned)b) << 16;
  return __builtin_bit_cast(float, u);
}

// ---------- async global->LDS, 16B per lane (dest = uniform base + lane*16)
__device__ __forceinline__ void gl_lds16(const ushort_t* g, ushort_t* l) {
  typedef __attribute__((address_space(1))) void gvoid;
  typedef __attribute__((address_space(3))) void lvoid;
  __builtin_amdgcn_global_load_lds((gvoid*)(ushort_t*)g, (lvoid*)l, 16, 0, 0);
}

// ---------- kernel 1: merged prep — x/wq/wp f32->bf16 convert + bias gather.
__global__ void k_prep(const float* __restrict__ x, ushort_t* __restrict__ xh,
                       const float* __restrict__ wq, ushort_t* __restrict__ wqh,
                       const float* __restrict__ wp, ushort_t* __restrict__ wph,
                       const float* __restrict__ table, const int* __restrict__ rel_idx,
                       float* __restrict__ bias) {
  int blk = blockIdx.x, tid = threadIdx.x;
  if (blk < 3136) {
    long i0 = (long)blk*256 + tid;
    #pragma unroll
    for (int rep = 0; rep < 8; rep++) {
      long i = i0 + (long)rep*802816;
      float4 v0 = ((const float4*)x)[2*i];
      float4 v1 = ((const float4*)x)[2*i + 1];
      s16x8 pk;
      pk[0] = (short)f2bf(v0.x); pk[1] = (short)f2bf(v0.y);
      pk[2] = (short)f2bf(v0.z); pk[3] = (short)f2bf(v0.w);
      pk[4] = (short)f2bf(v1.x); pk[5] = (short)f2bf(v1.y);
      pk[6] = (short)f2bf(v1.z); pk[7] = (short)f2bf(v1.w);
      *(s16x8*)&xh[i*8] = pk;
    }
  } else if (blk < 3648) {
    const float* src; ushort_t* dst; long i;
    if (blk < 3520) { src = wq; dst = wqh; i = (long)(blk - 3136)*256 + tid; }
    else            { src = wp; dst = wph; i = (long)(blk - 3520)*256 + tid; }
    float4 v0 = ((const float4*)src)[2*i];
    float4 v1 = ((const float4*)src)[2*i + 1];
    s16x8 pk;
    pk[0] = (short)f2bf(v0.x); pk[1] = (short)f2bf(v0.y);
    pk[2] = (short)f2bf(v0.z); pk[3] = (short)f2bf(v0.w);
    pk[4] = (short)f2bf(v1.x); pk[5] = (short)f2bf(v1.y);
    pk[6] = (short)f2bf(v1.z); pk[7] = (short)f2bf(v1.w);
    *(s16x8*)&dst[i*8] = pk;
  } else {
    int i0 = ((blk - 3648)*256 + tid)*4;     // 65536 total
    #pragma unroll
    for (int j = 0; j < 4; j++) {
      int i = i0 + j;
      int h = i >> 12, rc = i & 4095;
      bias[i] = table[rel_idx[rc] * 16 + h];
    }
  }
}

// ================= shared 4-phase counted-vmcnt loop (r12 config, HW-validated):
// 256x256 tile, 8 waves (2x4), BK=64, 8 K-tiles, 2 load-bearing barriers/tile.
struct GemmCtx {
  ushort_t* lds;
  const ushort_t *pA0, *pA1, *pB0, *pB1;
  int w, lane, wm, wn;
};

template<int BUFP, int KH, int RH, int SSEL, int SBUFP, int SU, int VM, bool BAR>
__device__ __forceinline__ void phase(const GemmCtx& C, f32x4 (&acc)[8][4], s16x8 (&bf)[4], int stau) {
  s16x8 af[4];
  #pragma unroll
  for (int t = 0; t < 4; t++)
    af[t] = *(const s16x8*)&C.lds[BUFP*32768 + ((C.wm*8 + RH*4 + t)*2 + KH)*512 + C.lane*8];
  if constexpr (RH == 0) {
    #pragma unroll
    for (int t = 0; t < 4; t++)
      bf[t] = *(const s16x8*)&C.lds[BUFP*32768 + 16384 + ((C.wn*4 + t)*2 + KH)*512 + C.lane*8];
  }
  if constexpr (SSEL == 0) {
    gl_lds16(C.pA0 + stau*64 + SU*32, C.lds + SBUFP*32768 + (4*C.w + SU)*512);
    gl_lds16(C.pA1 + stau*64 + SU*32, C.lds + SBUFP*32768 + (4*C.w + 2 + SU)*512);
  } else if constexpr (SSEL == 1) {
    gl_lds16(C.pB0 + stau*64 + SU*32, C.lds + SBUFP*32768 + 16384 + (4*C.w + SU)*512);
    gl_lds16(C.pB1 + stau*64 + SU*32, C.lds + SBUFP*32768 + 16384 + (4*C.w + 2 + SU)*512);
  }
  if constexpr (VM == 8) asm volatile("s_waitcnt vmcnt(8)" ::: "memory");
  else if constexpr (VM == 4) asm volatile("s_waitcnt vmcnt(4)" ::: "memory");
  else if constexpr (VM == 0) asm volatile("s_waitcnt vmcnt(0)" ::: "memory");
  __builtin_amdgcn_s_setprio(1);
  #pragma unroll
  for (int ta = 0; ta < 4; ta++)
    #pragma unroll
    for (int tb = 0; tb < 4; tb++)
      acc[RH*4 + ta][tb] = __builtin_amdgcn_mfma_f32_16x16x32_bf16(af[ta], bf[tb], acc[RH*4 + ta][tb], 0, 0, 0);
  __builtin_amdgcn_s_setprio(0);
  if constexpr (BAR) __builtin_amdgcn_s_barrier();
}

template<int BUFP, bool S12, bool S34, int VM2, int VM4>
__device__ __forceinline__ void ktile(const GemmCtx& C, f32x4 (&acc)[8][4], int tau) {
  s16x8 bf[4];
  phase<BUFP, 0, 0, S12 ? 0 : -1, BUFP^1, 1, -1,  false>(C, acc, bf, tau + 1);
  phase<BUFP, 0, 1, S12 ? 1 : -1, BUFP^1, 1, VM2, true >(C, acc, bf, tau + 1);
  phase<BUFP, 1, 0, S34 ? 0 : -1, BUFP,   0, -1,  false>(C, acc, bf, tau + 2);
  phase<BUFP, 1, 1, S34 ? 1 : -1, BUFP,   0, VM4, true >(C, acc, bf, tau + 2);
}

__device__ __forceinline__ void run_gemm_loop(const GemmCtx& C, f32x4 (&acc)[8][4]) {
  ushort_t* lds = C.lds;
  const int w = C.w;
  gl_lds16(C.pA0 +  0, lds + (4*w + 0)*512);
  gl_lds16(C.pA1 +  0, lds + (4*w + 2)*512);
  gl_lds16(C.pB0 +  0, lds + 16384 + (4*w + 0)*512);
  gl_lds16(C.pB1 +  0, lds + 16384 + (4*w + 2)*512);
  gl_lds16(C.pA0 + 32, lds + (4*w + 1)*512);
  gl_lds16(C.pA1 + 32, lds + (4*w + 3)*512);
  gl_lds16(C.pB0 + 32, lds + 16384 + (4*w + 1)*512);
  gl_lds16(C.pB1 + 32, lds + 16384 + (4*w + 3)*512);
  gl_lds16(C.pA0 + 64, lds + 32768 + (4*w + 0)*512);
  gl_lds16(C.pA1 + 64, lds + 32768 + (4*w + 2)*512);
  gl_lds16(C.pB0 + 64, lds + 32768 + 16384 + (4*w + 0)*512);
  gl_lds16(C.pB1 + 64, lds + 32768 + 16384 + (4*w + 2)*512);
  asm volatile("s_waitcnt vmcnt(4)" ::: "memory");
  __builtin_amdgcn_s_barrier();

  for (int kt = 0; kt < 6; kt += 2) {
    ktile<0, true, true, 8, 8>(C, acc, kt);
    ktile<1, true, true, 8, 8>(C, acc, kt + 1);
  }
  ktile<0, true,  false, 8, 4>(C, acc, 6);   // tail: vmcnt(4) guards tile7 kh0
  ktile<1, false, false, 0, -1>(C, acc, 7);  // tail: vmcnt(0) guards tile7 kh1
}

// ================= QKV GEMM (r12 config; best-measured 242 µs).
__global__ __launch_bounds__(512, 2) void k_gemm_qkv(
    const ushort_t* __restrict__ xh, const ushort_t* __restrict__ wh,
    ushort_t* __restrict__ qh, ushort_t* __restrict__ kh, ushort_t* __restrict__ vt) {
  extern __shared__ __align__(16) ushort_t lds[];
  const int tid = threadIdx.x, w = tid >> 6, lane = tid & 63;
  const int g = lane >> 4, l15 = lane & 15;
  const int wm = w >> 2, wn = w & 3;
  int flat = blockIdx.x;                 // 2352 = 8*294, bijective XCD swizzle
  int swz = (flat & 7) * 294 + (flat >> 3);
  int bx = swz % 6, by = swz / 6;        // bx fastest -> A-panel L2 reuse per XCD

  GemmCtx C;
  C.lds = lds;
  C.pA0 = xh + ((size_t)by*256 + (size_t)(2*w)*16 + l15)*512 + g*8;
  C.pA1 = C.pA0 + 16*512;
  C.pB0 = wh + ((size_t)bx*256 + (size_t)(2*w)*16 + l15)*512 + g*8;
  C.pB1 = C.pB0 + 16*512;
  C.w = w; C.lane = lane; C.wm = wm; C.wn = wn;

  f32x4 acc[8][4];
  #pragma unroll
  for (int r = 0; r < 8; r++)
    #pragma unroll
    for (int c = 0; c < 4; c++) acc[r][c] = (f32x4){0.f, 0.f, 0.f, 0.f};

  run_gemm_loop(C, acc);

  // ---- epilogue: acc -> LDS (swizzled, conflict-free), coalesced stores.
  asm volatile("" ::: "memory");
  const int sel = bx >> 1;
  if (sel < 2) {
    #pragma unroll
    for (int ra = 0; ra < 8; ra++)
      #pragma unroll
      for (int tb = 0; tb < 4; tb++)
        #pragma unroll
        for (int j = 0; j < 4; j++) {
          int row = wm*128 + ra*16 + g*4 + j;
          int col = wn*64 + tb*16 + l15;
          int r = (row >> 6)*8 + (col >> 5);
          int n = row & 63, d = col & 31;
          int byte = r*4096 + ((n*64 + d*2) ^ ((n & 12) << 3));
          *(ushort_t*)((char*)lds + byte) = f2bf(acc[ra][tb][j]);
        }
  } else {
    #pragma unroll
    for (int ra = 0; ra < 8; ra++)
      #pragma unroll
      for (int tb = 0; tb < 4; tb++) {
        int row0 = wm*128 + ra*16 + g*4;
        int col = wn*64 + tb*16 + l15;
        int r = (row0 >> 6)*8 + (col >> 5);
        int n0 = row0 & 63, d = col & 31;
        u64_t pk = (u64_t)f2bf(acc[ra][tb][0])
                 | ((u64_t)f2bf(acc[ra][tb][1]) << 16)
                 | ((u64_t)f2bf(acc[ra][tb][2]) << 32)
                 | ((u64_t)f2bf(acc[ra][tb][3]) << 48);
        int byte = r*4096 + ((d*128 + n0*2) ^ ((d & 7) << 4) ^ (((((d >> 3) ^ (n0 >> 3))) & 1) << 6));
        *(u64_t*)((char*)lds + byte) = pk;
      }
  }
  asm volatile("s_waitcnt lgkmcnt(0)" ::: "memory");
  __builtin_amdgcn_s_barrier();
  ushort_t* dst = (sel == 0) ? qh : (sel == 1) ? kh : vt;
  const int hbase = (bx & 1) * 8;
  #pragma unroll
  for (int it = 0; it < 16; it++) {
    int cg = it*512 + tid;
    int r = cg >> 8, inner = cg & 255;
    int byte;
    if (sel < 2) byte = r*4096 + ((inner*16) ^ (((inner >> 2) & 12) << 3));
    else         byte = r*4096 + ((inner*16) ^ (((inner >> 3) & 7) << 4) ^ ((((inner >> 6) ^ inner) & 1) << 6));
    s16x8 v = *(const s16x8*)((const char*)lds + byte);
    int b = by*4 + (r >> 3), h = hbase + (r & 7);
    *(s16x8*)&dst[(size_t)(b*16 + h)*2048 + inner*8] = v;
  }
}

// ================= proj GEMM: 128x256 tile, BK=32 (r18 config; L2-fed B panel).
__global__ __launch_bounds__(512, 4) void k_gemm_proj(
    const ushort_t* __restrict__ ah, const ushort_t* __restrict__ wh,
    const float* __restrict__ pb, float* __restrict__ out) {
  extern __shared__ __align__(16) ushort_t lds[];   // 3 bufs x 12288 ushort
  const int tid = threadIdx.x, w = tid >> 6, lane = tid & 63;
  const int g = lane >> 4, l15 = lane & 15;
  const int wm = w >> 2, wn = w & 3;
  int flat = blockIdx.x;                 // 1568 = 8*196, bijective XCD swizzle
  int swz = (flat & 7) * 196 + (flat >> 3);
  int bx = swz & 1, by = swz >> 1;

  const ushort_t* pA  = ah + ((size_t)(by*128 + w*16 + l15))*512 + g*8;
  const ushort_t* pB0 = wh + ((size_t)(bx*256 + (2*w)*16 + l15))*512 + g*8;
  const ushort_t* pB1 = pB0 + 16*512;

  f32x4 acc[4][4];
  #pragma unroll
  for (int r = 0; r < 4; r++)
    #pragma unroll
    for (int c = 0; c < 4; c++) acc[r][c] = (f32x4){0.f, 0.f, 0.f, 0.f};

  #pragma unroll
  for (int t0 = 0; t0 < 2; t0++) {
    ushort_t* buf = lds + t0*12288;
    gl_lds16(pA  + t0*32, buf + w*512);
    gl_lds16(pB0 + t0*32, buf + 4096 + (2*w)*512);
    gl_lds16(pB1 + t0*32, buf + 4096 + (2*w + 1)*512);
  }

  #pragma unroll
  for (int t = 0; t < 16; ++t) {
    if (t == 15) asm volatile("s_waitcnt vmcnt(0)" ::: "memory");
    else         asm volatile("s_waitcnt vmcnt(3)" ::: "memory");
    __builtin_amdgcn_s_barrier();
    if (t < 14) {
      ushort_t* bufS = lds + ((t + 2) % 3)*12288;
      gl_lds16(pA  + (t + 2)*32, bufS + w*512);
      gl_lds16(pB0 + (t + 2)*32, bufS + 4096 + (2*w)*512);
      gl_lds16(pB1 + (t + 2)*32, bufS + 4096 + (2*w + 1)*512);
    }
    ushort_t* buf = lds + (t % 3)*12288;
    s16x8 af[4], bf[4];
    #pragma unroll
    for (int ta = 0; ta < 4; ta++)
      af[ta] = *(const s16x8*)&buf[(wm*4 + ta)*512 + lane*8];
    #pragma unroll
    for (int tb = 0; tb < 4; tb++)
      bf[tb] = *(const s16x8*)&buf[4096 + (wn*4 + tb)*512 + lane*8];
    __builtin_amdgcn_s_setprio(1);
    #pragma unroll
    for (int ta = 0; ta < 4; ta++)
      #pragma unroll
      for (int tb = 0; tb < 4; tb++)
        acc[ta][tb] = __builtin_amdgcn_mfma_f32_16x16x32_bf16(af[ta], bf[tb], acc[ta][tb], 0, 0, 0);
    __builtin_amdgcn_s_setprio(0);
  }

  float pbv[4];
  #pragma unroll
  for (int tb = 0; tb < 4; tb++) pbv[tb] = pb[bx*256 + wn*64 + tb*16 + l15];
  #pragma unroll
  for (int ta = 0; ta < 4; ta++)
    #pragma unroll
    for (int tb = 0; tb < 4; tb++)
      #pragma unroll
      for (int j = 0; j < 4; j++) {
        int row = by*128 + wm*64 + ta*16 + g*4 + j;
        int col = bx*256 + wn*64 + tb*16 + l15;
        out[(size_t)row*512 + col] = acc[ta][tb][j] + pbv[tb];
      }
}

// ---------- kernel 3: attention. bf16 bias in LDS with XOR swizzle (8 KiB) +
// fragment-linear P (32 KiB) = exactly 40,960 B -> 4 blocks/CU (was 3).
// Bias read banks: (c*8 + l15>>1) XOR (g*8) -> 4 disjoint octets, 2-way free.
__global__ __launch_bounds__(256) void k_attn(
    const ushort_t* __restrict__ qh, const ushort_t* __restrict__ kh,
    const ushort_t* __restrict__ vt, const float* __restrict__ bias,
    ushort_t* __restrict__ aoh) {
  __shared__ ushort_t plds[4][4096];       // fragment-linear P, per wave (32 KiB)
  __shared__ ushort_t bldsh[4096];         // bf16 bias 64x64, XOR-swizzled (8 KiB)
  const int tid = threadIdx.x, w = tid >> 6, lane = tid & 63;
  const int g = lane >> 4, l15 = lane & 15;
  const int h = blockIdx.x & 15;
  const int b = (blockIdx.x >> 4)*4 + w;   // 392 b-groups x 16 heads
  const size_t base = (size_t)(b*16 + h) * 2048;

  // issue-early: q/k/v fragment loads (global->reg)
  s16x8 qf[4], kf[4];
  #pragma unroll
  for (int t = 0; t < 4; t++) {
    size_t o = base + (size_t)(t*16 + l15)*32 + g*8;
    qf[t] = *(const s16x8*)&qh[o];
    kf[t] = *(const s16x8*)&kh[o];
  }
  s16x8 vf[2][2];
  #pragma unroll
  for (int kt = 0; kt < 2; kt++)
    #pragma unroll
    for (int nt = 0; nt < 2; nt++)
      vf[kt][nt] = *(const s16x8*)&vt[base + (size_t)(nt*16 + l15)*64 + kt*32 + g*8];

  // cooperative bias stage: 4096 f32 -> bf16, XOR-swizzled addresses.
  const float* bh_ = bias + ((size_t)h << 12);
  #pragma unroll
  for (int it = 0; it < 4; it++) {
    int idx = it*1024 + tid*4;
    int rr = idx >> 6;
    f32x4 v = *(const f32x4*)&bh_[idx];
    u64_t pk = (u64_t)f2bf(v[0]) | ((u64_t)f2bf(v[1]) << 16)
             | ((u64_t)f2bf(v[2]) << 32) | ((u64_t)f2bf(v[3]) << 48);
    int byte = (idx*2) ^ ((rr & 12) << 3);
    *(u64_t*)((char*)bldsh + byte) = pk;
  }
  __syncthreads();

  f32x4 s[4][4];
  #pragma unroll
  for (int r = 0; r < 4; r++)
    #pragma unroll
    for (int c = 0; c < 4; c++) s[r][c] = (f32x4){0.f,0.f,0.f,0.f};
  #pragma unroll
  for (int r = 0; r < 4; r++)
    #pragma unroll
    for (int c = 0; c < 4; c++)
      s[r][c] = __builtin_amdgcn_mfma_f32_16x16x32_bf16(qf[r], kf[c], s[r][c], 0, 0, 0);

  const float invs = 0.17677669529663687f;  // 1/sqrt(32)
  #pragma unroll
  for (int r = 0; r < 4; r++)
    #pragma unroll
    for (int c = 0; c < 4; c++)
      #pragma unroll
      for (int j = 0; j < 4; j++) {
        int rr = r*16 + g*4 + j, cc = c*16 + l15;
        int byte = ((rr*64 + cc)*2) ^ ((rr & 12) << 3);
        s[r][c][j] = s[r][c][j]*invs + bf2f(*(const ushort_t*)((const char*)bldsh + byte));
      }

  #pragma unroll
  for (int r = 0; r < 4; r++)
    #pragma unroll
    for (int j = 0; j < 4; j++) {
      float mx = fmaxf(fmaxf(s[r][0][j], s[r][1][j]), fmaxf(s[r][2][j], s[r][3][j]));
      mx = fmaxf(mx, __shfl_xor(mx, 1));
      mx = fmaxf(mx, __shfl_xor(mx, 2));
      mx = fmaxf(mx, __shfl_xor(mx, 4));
      mx = fmaxf(mx, __shfl_xor(mx, 8));
      float p0 = __expf(s[r][0][j]-mx), p1 = __expf(s[r][1][j]-mx);
      float p2 = __expf(s[r][2][j]-mx), p3 = __expf(s[r][3][j]-mx);
      float sum = p0 + p1 + p2 + p3;
      sum += __shfl_xor(sum, 1);
      sum += __shfl_xor(sum, 2);
      sum += __shfl_xor(sum, 4);
      sum += __shfl_xor(sum, 8);
      float rv = 1.0f / sum;
      s[r][0][j] = p0*rv; s[r][1][j] = p1*rv; s[r][2][j] = p2*rv; s[r][3][j] = p3*rv;
    }

  ushort_t* Pw = plds[w];
  asm volatile("s_waitcnt lgkmcnt(0)" ::: "memory");
  __builtin_amdgcn_sched_barrier(0);
  #pragma unroll
  for (int r = 0; r < 4; r++)
    #pragma unroll
    for (int c = 0; c < 4; c++)
      #pragma unroll
      for (int j = 0; j < 4; j++) {
        int idx = ((c >> 1)*4 + r)*512 + ((((c & 1)*2) + (l15 >> 3))*16 + g*4 + j)*8 + (l15 & 7);
        Pw[idx] = f2bf(s[r][c][j]);
      }
  asm volatile("s_waitcnt lgkmcnt(0)" ::: "memory");
  __builtin_amdgcn_sched_barrier(0);

  s16x8 pf[4][2];
  #pragma unroll
  for (int ta = 0; ta < 4; ta++)
    #pragma unroll
    for (int kt = 0; kt < 2; kt++)
      pf[ta][kt] = *(const s16x8*)&Pw[(kt*4 + ta)*512 + lane*8];

  f32x4 o[4][2];
  #pragma unroll
  for (int ta = 0; ta < 4; ta++)
    #pragma unroll
    for (int nt = 0; nt < 2; nt++) o[ta][nt] = (f32x4){0.f,0.f,0.f,0.f};
  #pragma unroll
  for (int ta = 0; ta < 4; ta++)
    #pragma unroll
    for (int nt = 0; nt < 2; nt++)
      #pragma unroll
      for (int kt = 0; kt < 2; kt++)
        o[ta][nt] = __builtin_amdgcn_mfma_f32_16x16x32_bf16(pf[ta][kt], vf[kt][nt], o[ta][nt], 0, 0, 0);

  #pragma unroll
  for (int ta = 0; ta < 4; ta++)
    #pragma unroll
    for (int nt = 0; nt < 2; nt++)
      #pragma unroll
      for (int j = 0; j < 4; j++) {
        int rr = ta*16 + g*4 + j, dd = nt*16 + l15;
        aoh[((size_t)b*64 + rr)*512 + h*32 + dd] = f2bf(o[ta][nt][j]);
      }
}

extern "C" void kernel_launch(void* const* d_in, const int* in_sizes, int n_in,
                              void* d_out, int out_size, void* d_ws, size_t ws_size,
                              hipStream_t stream) {
  const float* x      = (const float*)d_in[0];
  const float* qkv_w  = (const float*)d_in[1];
  const float* table  = (const float*)d_in[2];
  const float* proj_w = (const float*)d_in[3];
  const float* proj_b = (const float*)d_in[4];
  const int*   rel_idx = (const int*)d_in[5];

  const size_t S1 = S1_ELEMS;
  const size_t need = (4*S1 + 786432 + 262144)*sizeof(ushort_t) + 65536*sizeof(float);
  if (ws_size < need) return;

  ushort_t* qh  = (ushort_t*)d_ws;
  ushort_t* kh  = qh + S1;
  ushort_t* vt  = kh + S1;
  ushort_t* xh  = vt + S1;        // reused as attention-out after QKV GEMM
  ushort_t* wqh = xh + S1;
  ushort_t* wph = wqh + 786432;
  float*    bias = (float*)(wph + 262144);
  ushort_t* aoh = xh;

  hipFuncSetAttribute((const void*)k_gemm_qkv,
                      hipFuncAttributeMaxDynamicSharedMemorySize, 131072);
  hipFuncSetAttribute((const void*)k_gemm_proj,
                      hipFuncAttributeMaxDynamicSharedMemorySize, 73728);

  k_prep<<<3712, 256, 0, stream>>>(x, xh, qkv_w, wqh, proj_w, wph, table, rel_idx, bias);
  k_gemm_qkv<<<2352, 512, 131072, stream>>>(xh, wqh, qh, kh, vt);
  k_attn<<<6272, 256, 0, stream>>>(qh, kh, vt, bias, aoh);
  k_gemm_proj<<<1568, 512, 73728, stream>>>(aoh, wph, proj_b, (float*)d_out);
}